// Round 13
// baseline (276.287 us; speedup 1.0000x reference)
//
#include <hip/hip_runtime.h>

// PaDiM training-branch accumulation + finalize — fused single kernel, take 2.
// embeddings: [B=32, C=192, P=3136] f32; means: [P,C] f32; covariances: [P,C,C] f32; n: int
// out: learned_means [P,C] ++ learned_covs [P,C,C]
//
// R13: 2 patches/block (grid 1568, XCD-bijective swizzle). R11's counters
// cleared the gather (FETCH 392MB, no amplification); its failures were
// (a) ds_write_u16 bank conflicts, (b) prefetch-ring spill, (c) 29% occ.
// Fixes: LDS = packed u32 EI[i] = {bf16 patch0 | bf16 patch1 << 16} written
// flat+consecutive (conflict-free); compute = R6's PROVEN fp32 SYRK engine
// (6x12 micro-tile, 2 passes) with a 1-op extract per value (j unrolled ->
// compile-time); no prefetch ring; LDS 26.1KB -> LB(256,4), 4 blocks/CU.
// No K1, no Et: emb read overlaps the cov RMW stream; 77MB round-trip gone.
// nt cov loads + nt 256B-segment stores (R5/R6-proven byte-exact WRITE).

#define BB 32
#define CC 192
#define PP 3136
#define II (BB * CC)   // 6144
#define EPSV 0.01f

typedef float nat_float4 __attribute__((ext_vector_type(4)));

__device__ __forceinline__ unsigned short f2bf(float f) {
    unsigned int u = __float_as_uint(f);
    u += 0x7fffu + ((u >> 16) & 1u);        // round-to-nearest-even
    return (unsigned short)(u >> 16);
}
__device__ __forceinline__ float exlo(unsigned int u) { return __uint_as_float(u << 16); }
__device__ __forceinline__ float exhi(unsigned int u) { return __uint_as_float(u & 0xffff0000u); }

__global__ __launch_bounds__(256, 4) void padim_fused(
    const float* __restrict__ emb,    // [B,C,P]
    const float* __restrict__ means,  // [P,C]
    const float* __restrict__ covs,   // [P,C,C]
    const int*   __restrict__ n_ptr,  // [1]
    float* __restrict__ out_means,    // [P,C]
    float* __restrict__ out_covs)     // [P,C,C]
{
    __shared__ unsigned int EI[II];             // 24576 B; word i=b*CC+c packs both patches
    __shared__ __align__(16) float m2[2][CC];   // 1536 B   (total 26112 B -> 4/CU)

    // XCD-bijective swizzle (1568 % 8 == 0): the 8 blocks sharing one 64B emb
    // line (16 patches) are sw-consecutive on the SAME XCD -> L2 absorbs the
    // 8B-granule gather (R11-measured: no fetch amplification).
    const int bid = blockIdx.x;
    const int sw = (bid & 7) * (PP / 2 / 8) + (bid >> 3);
    const int p0 = sw * 2;

    const int t = threadIdx.x;
    const float n_new = (float)(n_ptr[0] + BB);       // 128
    const float inv_nnew = 1.0f / n_new;
    const float inv_nm1 = 1.0f / (n_new - 1.0f);      // 1/127

    // ---- Stage: 24 independent float2 loads/thread; pack 2x bf16 -> u32;
    //      flat consecutive ds_write_b32 (conflict-free). ----
    #pragma unroll
    for (int k = 0; k < II / 256; ++k) {
        const int i = k * 256 + t;                // i = b*CC + c
        const float2 v = *reinterpret_cast<const float2*>(&emb[(size_t)i * PP + p0]);
        EI[i] = (unsigned int)f2bf(v.x) | ((unsigned int)f2bf(v.y) << 16);
    }
    __syncthreads();

    // ---- Means for both patches (one pass over the packed words) ----
    if (t < CC) {
        float s0 = 0.f, s1 = 0.f;
        #pragma unroll
        for (int b = 0; b < BB; ++b) {
            const unsigned int u = EI[b * CC + t];
            s0 += exlo(u);
            s1 += exhi(u);
        }
        const size_t i0 = (size_t)p0 * CC + t;
        const float mm0 = (means[i0] + s0) * inv_nnew;
        const float mm1 = (means[i0 + CC] + s1) * inv_nnew;
        m2[0][t] = mm0;
        m2[1][t] = mm1;
        out_means[i0] = mm0;
        out_means[i0 + CC] = mm1;
    }
    __syncthreads();   // last barrier; waves drift through the 4 SYRK rounds

    const int tx = t & 15;   // d: 3 groups of cols g*64 + tx*4
    const int ty = t >> 4;   // c: 6 rows per pass
    const int dbase0 = tx * 4;

    // ---- 4 rounds: patch j (unrolled, compile-time extract) x pass ----
    #pragma unroll
    for (int j = 0; j < 2; ++j) {
        const float* __restrict__ cov_p = covs + (size_t)(p0 + j) * CC * CC;
        float* __restrict__ out_p = out_covs + (size_t)(p0 + j) * CC * CC;
        const float* __restrict__ mj = &m2[j][0];

        float md[12];
        *reinterpret_cast<float4*>(&md[0]) = *reinterpret_cast<const float4*>(&mj[dbase0]);
        *reinterpret_cast<float4*>(&md[4]) = *reinterpret_cast<const float4*>(&mj[64 + dbase0]);
        *reinterpret_cast<float4*>(&md[8]) = *reinterpret_cast<const float4*>(&mj[128 + dbase0]);

        #pragma unroll 1
        for (int pass = 0; pass < 2; ++pass) {
            const int c0 = pass * 96 + ty * 6;

            float acc[6][12];
            #pragma unroll
            for (int i = 0; i < 6; ++i)
                #pragma unroll
                for (int jj = 0; jj < 12; ++jj) acc[i][jj] = 0.f;

            #pragma unroll 4
            for (int b = 0; b < BB; ++b) {
                const unsigned int* __restrict__ Eb = &EI[b * CC];
                const uint4 d0 = *reinterpret_cast<const uint4*>(&Eb[dbase0]);
                const uint4 d1 = *reinterpret_cast<const uint4*>(&Eb[64 + dbase0]);
                const uint4 d2 = *reinterpret_cast<const uint4*>(&Eb[128 + dbase0]);
                const uint2 cA = *reinterpret_cast<const uint2*>(&Eb[c0]);
                const uint2 cB = *reinterpret_cast<const uint2*>(&Eb[c0 + 2]);
                const uint2 cC = *reinterpret_cast<const uint2*>(&Eb[c0 + 4]);
                float ds[12], cs[6];
                if (j == 0) {
                    ds[0] = exlo(d0.x); ds[1] = exlo(d0.y); ds[2]  = exlo(d0.z); ds[3]  = exlo(d0.w);
                    ds[4] = exlo(d1.x); ds[5] = exlo(d1.y); ds[6]  = exlo(d1.z); ds[7]  = exlo(d1.w);
                    ds[8] = exlo(d2.x); ds[9] = exlo(d2.y); ds[10] = exlo(d2.z); ds[11] = exlo(d2.w);
                    cs[0] = exlo(cA.x); cs[1] = exlo(cA.y); cs[2]  = exlo(cB.x);
                    cs[3] = exlo(cB.y); cs[4] = exlo(cC.x); cs[5]  = exlo(cC.y);
                } else {
                    ds[0] = exhi(d0.x); ds[1] = exhi(d0.y); ds[2]  = exhi(d0.z); ds[3]  = exhi(d0.w);
                    ds[4] = exhi(d1.x); ds[5] = exhi(d1.y); ds[6]  = exhi(d1.z); ds[7]  = exhi(d1.w);
                    ds[8] = exhi(d2.x); ds[9] = exhi(d2.y); ds[10] = exhi(d2.z); ds[11] = exhi(d2.w);
                    cs[0] = exhi(cA.x); cs[1] = exhi(cA.y); cs[2]  = exhi(cB.x);
                    cs[3] = exhi(cB.y); cs[4] = exhi(cC.x); cs[5]  = exhi(cC.y);
                }
                #pragma unroll
                for (int i = 0; i < 6; ++i)
                    #pragma unroll
                    for (int jj = 0; jj < 12; ++jj)
                        acc[i][jj] = fmaf(cs[i], ds[jj], acc[i][jj]);
            }

            float mc[6];
            *reinterpret_cast<float2*>(&mc[0]) = *reinterpret_cast<const float2*>(&mj[c0]);
            *reinterpret_cast<float2*>(&mc[2]) = *reinterpret_cast<const float2*>(&mj[c0 + 2]);
            *reinterpret_cast<float2*>(&mc[4]) = *reinterpret_cast<const float2*>(&mj[c0 + 4]);

            // ---- Fused finalize + cov RMW (nt in, nt out; 256B segments) ----
            #pragma unroll
            for (int i = 0; i < 6; ++i) {
                const int c = c0 + i;
                const size_t row = (size_t)c * CC;
                const float nmc = n_new * mc[i];
                #pragma unroll
                for (int g = 0; g < 3; ++g) {
                    const int db = g * 64 + dbase0;
                    const nat_float4 cin = __builtin_nontemporal_load(
                        reinterpret_cast<const nat_float4*>(&cov_p[row + db]));
                    nat_float4 o;
                    o.x = (cin.x + acc[i][g*4+0] - nmc * md[g*4+0]) * inv_nm1;
                    o.y = (cin.y + acc[i][g*4+1] - nmc * md[g*4+1]) * inv_nm1;
                    o.z = (cin.z + acc[i][g*4+2] - nmc * md[g*4+2]) * inv_nm1;
                    o.w = (cin.w + acc[i][g*4+3] - nmc * md[g*4+3]) * inv_nm1;
                    const int dd = c - db;   // diagonal hits when 0 <= dd < 4
                    if (dd == 0) o.x += EPSV;
                    if (dd == 1) o.y += EPSV;
                    if (dd == 2) o.z += EPSV;
                    if (dd == 3) o.w += EPSV;
                    __builtin_nontemporal_store(o, reinterpret_cast<nat_float4*>(&out_p[row + db]));
                }
            }
        }
    }
}

extern "C" void kernel_launch(void* const* d_in, const int* in_sizes, int n_in,
                              void* d_out, int out_size, void* d_ws, size_t ws_size,
                              hipStream_t stream) {
    const float* emb   = (const float*)d_in[0];
    const float* means = (const float*)d_in[1];
    const float* covs  = (const float*)d_in[2];
    const int*   n_ptr = (const int*)d_in[3];

    float* out_means = (float*)d_out;                      // [P,C]
    float* out_covs  = (float*)d_out + (size_t)PP * CC;    // [P,C,C]

    hipLaunchKernelGGL(padim_fused, dim3(PP / 2), dim3(256), 0, stream,
                       emb, means, covs, n_ptr, out_means, out_covs);
}

// Round 14
// 204.067 us; speedup vs baseline: 1.3539x; 1.3539x over previous
//
#include <hip/hip_runtime.h>

// PaDiM training-branch accumulation + finalize.
// embeddings: [B=32, C=192, P=3136] f32; means: [P,C] f32; covariances: [P,C,C] f32; n: int
// out: learned_means [P,C] ++ learned_covs [P,C,C]
//
// R14 = R12 (champion, 204.5us) + K1 float2 loads (512B/wave-instr, was 256B).
// R12 proven bits kept verbatim: two-kernel pipeline (bf16 Et [P][II]),
// K2 = slab-split fp32 register SYRK (grid (PP,2), LB(256,4)), nt cov loads
// (R13 FETCH=309MB proves they still L3-hit; plain loads would thrash Et),
// nt 256B-segment stores (byte-exact WRITE_SIZE), XCD-friendly K1 tiling.
// Fusion is twice-falsified (R11: bank conflicts+spill; R13: 4 serial
// rounds/block kill parallelism) — not retried.

#define BB 32
#define CC 192
#define PP 3136
#define II (BB * CC)   // 6144
#define EPSV 0.01f

typedef float nat_float4 __attribute__((ext_vector_type(4)));
typedef float nat_float2 __attribute__((ext_vector_type(2)));

__device__ __forceinline__ unsigned short f2bf(float f) {
    unsigned int u = __float_as_uint(f);
    u += 0x7fffu + ((u >> 16) & 1u);        // round-to-nearest-even
    return (unsigned short)(u >> 16);
}

// ---------- Kernel 1: tiled transpose emb [II][PP] f32 -> Et [PP][II] bf16 ----------
__global__ __launch_bounds__(256) void transpose_kernel(
    const float* __restrict__ emb, unsigned short* __restrict__ Et)
{
    __shared__ float tile[64][65];          // +1 pad: 2-way-max bank aliasing
    const int i0 = blockIdx.x * 64;         // 96 tiles over II
    const int p0 = blockIdx.y * 64;         // 49 tiles over PP
    const int t = threadIdx.x;

    // ---- Load: float2 along p; 2 rows x 256B = 512B per wave instr ----
    const int q2 = t & 31;                  // p-pair index 0..31
    const int r8 = t >> 5;                  // 0..7
    #pragma unroll
    for (int k = 0; k < 8; ++k) {
        const int r = k * 8 + r8;           // i-local row
        const nat_float2 v = __builtin_nontemporal_load(
            reinterpret_cast<const nat_float2*>(&emb[(size_t)(i0 + r) * PP + p0 + 2 * q2]));
        tile[r][2 * q2]     = v.x;          // banks (r + 2q2)%32 -> 2-way, free
        tile[r][2 * q2 + 1] = v.y;
    }
    __syncthreads();

    // ---- Write: pack 2 bf16 -> u32; per instr 2 rows x 128B (R12-proven) ----
    const int tc = t & 63;
    const int tr4 = t >> 6;                 // 0..3
    const int q = tc & 31;                  // i-pair index 0..31
    const int hf = tc >> 5;                 // 0..1
    #pragma unroll
    for (int k = 0; k < 8; ++k) {
        const int prow = k * 8 + tr4 * 2 + hf;   // p-local row 0..63
        const unsigned int lo = (unsigned int)f2bf(tile[2 * q][prow]);
        const unsigned int hi = (unsigned int)f2bf(tile[2 * q + 1][prow]);
        unsigned int* dst = reinterpret_cast<unsigned int*>(
            Et + (size_t)(p0 + prow) * II + i0);
        dst[q] = lo | (hi << 16);
    }
}

// ---------- Kernel 2: per-patch-slab fp32 SYRK + finalize (R6/R12 engine) ----------
__global__ __launch_bounds__(256, 4) void padim_main(
    const unsigned short* __restrict__ Et,  // [P][II] bf16
    const float* __restrict__ means,        // [P,C]
    const float* __restrict__ covs,         // [P,C,C]
    const int*   __restrict__ n_ptr,        // [1]
    float* __restrict__ out_means,          // [P,C]
    float* __restrict__ out_covs)           // [P,C,C]
{
    __shared__ __align__(16) float E[II];   // 24 KB, flat [b*CC + c]
    __shared__ __align__(16) float m[CC];

    const int p = blockIdx.x;
    const int slab = blockIdx.y;            // 0: rows 0..95, 1: rows 96..191
    const int t = threadIdx.x;

    const float n_new = (float)(n_ptr[0] + BB);       // 128
    const float inv_nnew = 1.0f / n_new;
    const float inv_nm1 = 1.0f / (n_new - 1.0f);      // 1/127

    // ---- Stage Et[p] (bf16) -> E (f32): 3 coalesced uint4 loads/thread ----
    {
        const uint4* __restrict__ src = reinterpret_cast<const uint4*>(Et + (size_t)p * II);
        #pragma unroll
        for (int k = 0; k < 3; ++k) {
            const int idx = k * 256 + t;            // 0..767 (16B chunks)
            const uint4 v = src[idx];
            float f[8];
            f[0] = __uint_as_float(v.x << 16); f[1] = __uint_as_float(v.x & 0xffff0000u);
            f[2] = __uint_as_float(v.y << 16); f[3] = __uint_as_float(v.y & 0xffff0000u);
            f[4] = __uint_as_float(v.z << 16); f[5] = __uint_as_float(v.z & 0xffff0000u);
            f[6] = __uint_as_float(v.w << 16); f[7] = __uint_as_float(v.w & 0xffff0000u);
            float4* dst = reinterpret_cast<float4*>(&E[idx * 8]);
            dst[0] = make_float4(f[0], f[1], f[2], f[3]);
            dst[1] = make_float4(f[4], f[5], f[6], f[7]);
        }
    }
    __syncthreads();

    // ---- Means (both slabs compute; slab 0 writes) ----
    if (t < CC) {
        float s = 0.0f;
        #pragma unroll
        for (int b = 0; b < BB; ++b) s += E[b * CC + t];
        const float mm = (means[(size_t)p * CC + t] + s) * inv_nnew;
        m[t] = mm;
        if (slab == 0) out_means[(size_t)p * CC + t] = mm;
    }
    __syncthreads();

    const int tx = t & 15;   // d: 3 groups of cols g*64 + tx*4
    const int ty = t >> 4;   // c: 6 rows within this slab's 96
    const int dbase0 = tx * 4;
    const int c0 = slab * 96 + ty * 6;

    const float* __restrict__ cov_p = covs + (size_t)p * CC * CC;
    float* __restrict__ out_p = out_covs + (size_t)p * CC * CC;

    float md[12];
    *reinterpret_cast<float4*>(&md[0]) = *reinterpret_cast<const float4*>(&m[dbase0]);
    *reinterpret_cast<float4*>(&md[4]) = *reinterpret_cast<const float4*>(&m[64 + dbase0]);
    *reinterpret_cast<float4*>(&md[8]) = *reinterpret_cast<const float4*>(&m[128 + dbase0]);

    float acc[6][12];
    #pragma unroll
    for (int i = 0; i < 6; ++i)
        #pragma unroll
        for (int j = 0; j < 12; ++j) acc[i][j] = 0.f;

    #pragma unroll 4
    for (int b = 0; b < BB; ++b) {
        const float* __restrict__ Eb = E + b * CC;
        float cs[6], ds[12];
        *reinterpret_cast<float4*>(&ds[0]) = *reinterpret_cast<const float4*>(&Eb[dbase0]);
        *reinterpret_cast<float4*>(&ds[4]) = *reinterpret_cast<const float4*>(&Eb[64 + dbase0]);
        *reinterpret_cast<float4*>(&ds[8]) = *reinterpret_cast<const float4*>(&Eb[128 + dbase0]);
        *reinterpret_cast<float2*>(&cs[0]) = *reinterpret_cast<const float2*>(&Eb[c0]);
        *reinterpret_cast<float2*>(&cs[2]) = *reinterpret_cast<const float2*>(&Eb[c0 + 2]);
        *reinterpret_cast<float2*>(&cs[4]) = *reinterpret_cast<const float2*>(&Eb[c0 + 4]);
        #pragma unroll
        for (int i = 0; i < 6; ++i)
            #pragma unroll
            for (int j = 0; j < 12; ++j)
                acc[i][j] = fmaf(cs[i], ds[j], acc[i][j]);
    }

    float mc[6];
    *reinterpret_cast<float2*>(&mc[0]) = *reinterpret_cast<const float2*>(&m[c0]);
    *reinterpret_cast<float2*>(&mc[2]) = *reinterpret_cast<const float2*>(&m[c0 + 2]);
    *reinterpret_cast<float2*>(&mc[4]) = *reinterpret_cast<const float2*>(&m[c0 + 4]);

    // ---- Fused finalize + cov RMW stream (nt in, nt out; 256B segments) ----
    #pragma unroll
    for (int i = 0; i < 6; ++i) {
        const int c = c0 + i;
        const size_t row = (size_t)c * CC;
        const float nmc = n_new * mc[i];
        #pragma unroll
        for (int g = 0; g < 3; ++g) {
            const int db = g * 64 + dbase0;
            const nat_float4 cin = __builtin_nontemporal_load(
                reinterpret_cast<const nat_float4*>(&cov_p[row + db]));
            nat_float4 o;
            o.x = (cin.x + acc[i][g*4+0] - nmc * md[g*4+0]) * inv_nm1;
            o.y = (cin.y + acc[i][g*4+1] - nmc * md[g*4+1]) * inv_nm1;
            o.z = (cin.z + acc[i][g*4+2] - nmc * md[g*4+2]) * inv_nm1;
            o.w = (cin.w + acc[i][g*4+3] - nmc * md[g*4+3]) * inv_nm1;
            const int dd = c - db;   // diagonal hits when 0 <= dd < 4
            if (dd == 0) o.x += EPSV;
            if (dd == 1) o.y += EPSV;
            if (dd == 2) o.z += EPSV;
            if (dd == 3) o.w += EPSV;
            __builtin_nontemporal_store(o, reinterpret_cast<nat_float4*>(&out_p[row + db]));
        }
    }
}

// ---------- Fallback (ws too small): single-kernel with direct gather ----
__global__ __launch_bounds__(256, 3) void padim_fallback(
    const float* __restrict__ emb, const float* __restrict__ means,
    const float* __restrict__ covs, const int* __restrict__ n_ptr,
    float* __restrict__ out_means, float* __restrict__ out_covs)
{
    __shared__ __align__(16) float E[II];
    __shared__ __align__(16) float m[CC];
    const int bid = blockIdx.x;
    const int p = (bid & 7) * (PP / 8) + (bid >> 3);
    const int t = threadIdx.x;
    const float n_new = (float)(n_ptr[0] + BB);
    const float inv_nnew = 1.0f / n_new;
    const float inv_nm1 = 1.0f / (n_new - 1.0f);
    #pragma unroll
    for (int k = 0; k < II / 256; ++k) {
        const int i = t + k * 256;
        E[i] = emb[(size_t)i * PP + p];
    }
    __syncthreads();
    if (t < CC) {
        float s = 0.0f;
        #pragma unroll
        for (int b = 0; b < BB; ++b) s += E[b * CC + t];
        const float mm = (means[(size_t)p * CC + t] + s) * inv_nnew;
        m[t] = mm;
        out_means[(size_t)p * CC + t] = mm;
    }
    __syncthreads();
    const int tx = t & 15, ty = t >> 4;
    const int dbase0 = tx * 4;
    const float* __restrict__ cov_p = covs + (size_t)p * CC * CC;
    float* __restrict__ out_p = out_covs + (size_t)p * CC * CC;
    float md[12];
    *reinterpret_cast<float4*>(&md[0]) = *reinterpret_cast<const float4*>(&m[dbase0]);
    *reinterpret_cast<float4*>(&md[4]) = *reinterpret_cast<const float4*>(&m[64 + dbase0]);
    *reinterpret_cast<float4*>(&md[8]) = *reinterpret_cast<const float4*>(&m[128 + dbase0]);
    #pragma unroll
    for (int pass = 0; pass < 2; ++pass) {
        const int c0 = pass * 96 + ty * 6;
        float acc[6][12];
        #pragma unroll
        for (int i = 0; i < 6; ++i)
            #pragma unroll
            for (int j = 0; j < 12; ++j) acc[i][j] = 0.f;
        #pragma unroll 4
        for (int b = 0; b < BB; ++b) {
            const float* __restrict__ Eb = E + b * CC;
            float cs[6], ds[12];
            *reinterpret_cast<float4*>(&ds[0]) = *reinterpret_cast<const float4*>(&Eb[dbase0]);
            *reinterpret_cast<float4*>(&ds[4]) = *reinterpret_cast<const float4*>(&Eb[64 + dbase0]);
            *reinterpret_cast<float4*>(&ds[8]) = *reinterpret_cast<const float4*>(&Eb[128 + dbase0]);
            *reinterpret_cast<float2*>(&cs[0]) = *reinterpret_cast<const float2*>(&Eb[c0]);
            *reinterpret_cast<float2*>(&cs[2]) = *reinterpret_cast<const float2*>(&Eb[c0 + 2]);
            *reinterpret_cast<float2*>(&cs[4]) = *reinterpret_cast<const float2*>(&Eb[c0 + 4]);
            #pragma unroll
            for (int i = 0; i < 6; ++i)
                #pragma unroll
                for (int j = 0; j < 12; ++j)
                    acc[i][j] = fmaf(cs[i], ds[j], acc[i][j]);
        }
        float mc[6];
        *reinterpret_cast<float2*>(&mc[0]) = *reinterpret_cast<const float2*>(&m[c0]);
        *reinterpret_cast<float2*>(&mc[2]) = *reinterpret_cast<const float2*>(&m[c0 + 2]);
        *reinterpret_cast<float2*>(&mc[4]) = *reinterpret_cast<const float2*>(&m[c0 + 4]);
        #pragma unroll
        for (int i = 0; i < 6; ++i) {
            const int c = c0 + i;
            const size_t row = (size_t)c * CC;
            const float nmc = n_new * mc[i];
            #pragma unroll
            for (int g = 0; g < 3; ++g) {
                const int db = g * 64 + dbase0;
                const float4 cin = *reinterpret_cast<const float4*>(&cov_p[row + db]);
                float4 o;
                o.x = (cin.x + acc[i][g*4+0] - nmc * md[g*4+0]) * inv_nm1;
                o.y = (cin.y + acc[i][g*4+1] - nmc * md[g*4+1]) * inv_nm1;
                o.z = (cin.z + acc[i][g*4+2] - nmc * md[g*4+2]) * inv_nm1;
                o.w = (cin.w + acc[i][g*4+3] - nmc * md[g*4+3]) * inv_nm1;
                const int dd = c - db;
                if (dd == 0) o.x += EPSV;
                if (dd == 1) o.y += EPSV;
                if (dd == 2) o.z += EPSV;
                if (dd == 3) o.w += EPSV;
                *reinterpret_cast<float4*>(&out_p[row + db]) = o;
            }
        }
    }
}

extern "C" void kernel_launch(void* const* d_in, const int* in_sizes, int n_in,
                              void* d_out, int out_size, void* d_ws, size_t ws_size,
                              hipStream_t stream) {
    const float* emb   = (const float*)d_in[0];
    const float* means = (const float*)d_in[1];
    const float* covs  = (const float*)d_in[2];
    const int*   n_ptr = (const int*)d_in[3];

    float* out_means = (float*)d_out;                      // [P,C]
    float* out_covs  = (float*)d_out + (size_t)PP * CC;    // [P,C,C]

    const size_t et_bytes = (size_t)PP * II * sizeof(unsigned short);   // 38.5 MB
    if (ws_size >= et_bytes) {
        unsigned short* Et = (unsigned short*)d_ws;
        hipLaunchKernelGGL(transpose_kernel, dim3(II / 64, PP / 64), dim3(256),
                           0, stream, emb, Et);
        hipLaunchKernelGGL(padim_main, dim3(PP, 2), dim3(256), 0, stream,
                           Et, means, covs, n_ptr, out_means, out_covs);
    } else {
        hipLaunchKernelGGL(padim_fallback, dim3(PP), dim3(256), 0, stream,
                           emb, means, covs, n_ptr, out_means, out_covs);
    }
}